// Round 5
// baseline (492.137 us; speedup 1.0000x reference)
//
#include <hip/hip_runtime.h>

// Reference reduces to a center crop (coords are fp32-exact integers i+16.0):
//   data_out[b,c,i,j,k] = data[b,c,i+16,j+16,k+16]
//   seg_out  = seg[:, :, 16:176, 16:176, 16:176]
// Shapes: in 2x (4,2,192,192,192) f32, out 2x (4,2,160,160,160) f32 concat-flat.
//
// Ladder: R0 161.7 (2-deep, nt all) | R1 172.8 (1280blk imbalance) |
// R2 161.6 (8-deep, nt all) | R3 165.8 (plain LOADS regress => nt loads good)
// | R4 ~158.2 (per-wave stream separation, nt all). All pinned at
// ~2.6-3.6 TB/s combined while fill=6.4 and RMSNorm-class mixed R/W=4.9
// on this chip => not a structural mixed-traffic floor.
// R5: single variable vs R4 -- PLAIN stores (nt kept on loads). nt-store
// (stream policy: L2 evict-first, MALL no-allocate) pushes every 128B line
// at DRAM in issue order; plain stores write-allocate dirty in L2/MALL and
// let the hierarchy batch writebacks -- the path the 6.4 TB/s fill uses.
// nt-stores were present in EVERY prior round, never isolated.

constexpr unsigned P    = 160;                 // patch edge
constexpr unsigned S    = 192;                 // source edge
constexpr unsigned OFF  = 16;                  // crop offset
constexpr unsigned BC   = 8;                   // 4*2 volumes per tensor
constexpr unsigned ROW4 = P / 4;               // 40 f4 per out row
constexpr unsigned SROW4   = S / 4;            // 48
constexpr unsigned SPLANE4 = S * S / 4;        // 9216
constexpr unsigned SVOL4   = S * S * S / 4;    // 1769472
constexpr unsigned OUT4 = BC * P * P * ROW4;   // 8,192,000 f4 per tensor
constexpr unsigned GRID_HALF = OUT4 / 1024;    // 8000 blocks per tensor

using f4 = __attribute__((ext_vector_type(4))) float;

__global__ __launch_bounds__(256) void crop_copy_kernel(
    const f4* __restrict__ data,
    const f4* __restrict__ seg,
    f4* __restrict__ out)
{
    const bool is_seg  = blockIdx.x >= GRID_HALF;           // scalar branch
    const f4* __restrict__ src_buf = is_seg ? seg : data;
    f4* __restrict__ dst           = out + (is_seg ? OUT4 : 0u);
    const unsigned b  = blockIdx.x - (is_seg ? GRID_HALF : 0u);
    const unsigned o0 = b * 1024u + threadIdx.x;            // + 256k, k=0..3

    unsigned src[4];
#pragma unroll
    for (unsigned k = 0; k < 4; ++k) {
        const unsigned o   = o0 + 256u * k;
        const unsigned w4  = o % ROW4;
        const unsigned row = o / ROW4;
        const unsigned h   = row % P;
        const unsigned t   = row / P;
        const unsigned d   = t % P;
        const unsigned bc  = t / P;
        src[k] = bc * SVOL4 + (d + OFF) * SPLANE4 + (h + OFF) * SROW4
               + (OFF / 4) + w4;
    }

    // 4 independent nt loads in flight from ONE buffer, then 4 PLAIN stores.
    f4 a0 = __builtin_nontemporal_load(&src_buf[src[0]]);
    f4 a1 = __builtin_nontemporal_load(&src_buf[src[1]]);
    f4 a2 = __builtin_nontemporal_load(&src_buf[src[2]]);
    f4 a3 = __builtin_nontemporal_load(&src_buf[src[3]]);

    dst[o0]        = a0;
    dst[o0 + 256u] = a1;
    dst[o0 + 512u] = a2;
    dst[o0 + 768u] = a3;
}

extern "C" void kernel_launch(void* const* d_in, const int* in_sizes, int n_in,
                              void* d_out, int out_size, void* d_ws, size_t ws_size,
                              hipStream_t stream)
{
    const f4* data = (const f4*)d_in[0];
    const f4* seg  = (const f4*)d_in[1];
    f4* out = (f4*)d_out;

    constexpr unsigned block = 256;
    constexpr unsigned grid  = 2 * GRID_HALF;  // 16000 blocks, no tail
    crop_copy_kernel<<<grid, block, 0, stream>>>(data, seg, out);
}

// Round 6
// 485.691 us; speedup vs baseline: 1.0133x; 1.0133x over previous
//
#include <hip/hip_runtime.h>

// Reference reduces to a center crop (coords are fp32-exact integers i+16.0):
//   data_out[b,c,i,j,k] = data[b,c,i+16,j+16,k+16]
//   seg_out  = seg[:, :, 16:176, 16:176, 16:176]
// Shapes: in 2x (4,2,192,192,192) f32, out 2x (4,2,160,160,160) f32 concat-flat.
//
// Ladder: R0 161.7 | R1 172.8 (imbalance) | R2 161.6 | R3 165.8 (plain loads
// worse) | R4 ~158 BEST (stream-split, nt both) | R5 161.7 (plain stores
// worse). All pinned ~3.5 TB/s data-plane while m13 copy = 6.29 TB/s.
// Wave structure / MLP / grid / cache policy / stream mixing all exonerated.
// Last difference vs the 6.29 copy: the READ REQUEST PATTERN -- each out row
// is a 640B request window starting 64B into a 128B line (misaligned wave
// segments, partial lines, 128B hole per 768B row).
// R6: realign through LDS. Block = 32 out rows of one (tensor,bc,d) plane.
//   read  : 32 full src rows = 1536 f4, dense, 128B-aligned (row start is a
//           768B boundary) -> LDS (24KB)
//   write : 32 out rows = 1280 f4 = ONE dense aligned contiguous region,
//           sourced from LDS at the +4 f4 shift (<=2-way bank alias = free).
// Both global streams are now exactly m13-copy-shaped. nt both (best flags).
// Grid 12800 blocks (self-balancing), 6 blocks/CU by LDS.

constexpr unsigned P    = 160;                 // patch edge
constexpr unsigned S    = 192;                 // source edge
constexpr unsigned OFF  = 16;                  // crop offset (floats)
constexpr unsigned BC   = 8;                   // 4*2 volumes per tensor
constexpr unsigned ROW4 = P / 4;               // 40 f4 per out row
constexpr unsigned SROW4   = S / 4;            // 48 f4 per src row
constexpr unsigned SPLANE4 = S * S / 4;        // 9216
constexpr unsigned SVOL4   = S * S * S / 4;    // 1769472
constexpr unsigned OUT4 = BC * P * P * ROW4;   // 8,192,000 f4 per tensor

constexpr unsigned RPB   = 32;                 // out rows per block
constexpr unsigned BPP   = P / RPB;            // 5 blocks per plane
constexpr unsigned BPT   = BC * P * BPP;       // 6400 blocks per tensor
constexpr unsigned LDSF4 = RPB * SROW4;        // 1536 f4 staged (24 KB)
constexpr unsigned OUTF4 = RPB * ROW4;         // 1280 f4 written

using f4 = __attribute__((ext_vector_type(4))) float;

__global__ __launch_bounds__(256) void crop_copy_kernel(
    const f4* __restrict__ data,
    const f4* __restrict__ seg,
    f4* __restrict__ out)
{
    __shared__ f4 lds[LDSF4];

    const unsigned gb     = blockIdx.x;
    const bool     is_seg = gb >= BPT;                    // scalar branch
    const f4* __restrict__ src_buf = is_seg ? seg : data;
    const unsigned b  = gb - (is_seg ? BPT : 0u);
    const unsigned bc = b / (P * BPP);                    // / 800
    const unsigned r2 = b - bc * (P * BPP);
    const unsigned d  = r2 / BPP;
    const unsigned h0 = (r2 - d * BPP) * RPB;             // 0,32,..,128
    const unsigned t  = threadIdx.x;

    // ---- read: 32 full aligned src rows -> LDS (dense, 128B-aligned) ----
    const unsigned sbase = bc * SVOL4 + (d + OFF) * SPLANE4 + (h0 + OFF) * SROW4;

    f4 v0 = __builtin_nontemporal_load(&src_buf[sbase + t]);
    f4 v1 = __builtin_nontemporal_load(&src_buf[sbase + t +  256u]);
    f4 v2 = __builtin_nontemporal_load(&src_buf[sbase + t +  512u]);
    f4 v3 = __builtin_nontemporal_load(&src_buf[sbase + t +  768u]);
    f4 v4 = __builtin_nontemporal_load(&src_buf[sbase + t + 1024u]);
    f4 v5 = __builtin_nontemporal_load(&src_buf[sbase + t + 1280u]);

    lds[t]          = v0;
    lds[t +  256u]  = v1;
    lds[t +  512u]  = v2;
    lds[t +  768u]  = v3;
    lds[t + 1024u]  = v4;
    lds[t + 1280u]  = v5;

    __syncthreads();

    // ---- write: 32 out rows as ONE dense aligned region, shifted via LDS ----
    const unsigned obase = (is_seg ? OUT4 : 0u)
                         + ((bc * P + d) * P + h0) * ROW4;

#pragma unroll
    for (unsigned k = 0; k < 5; ++k) {
        const unsigned oidx = t + 256u * k;               // 0..1279
        const unsigned r    = oidx / ROW4;                // out row in block
        const unsigned w    = oidx - r * ROW4;            // f4 within row
        f4 val = lds[r * SROW4 + (OFF / 4) + w];
        __builtin_nontemporal_store(val, &out[obase + oidx]);
    }
}

extern "C" void kernel_launch(void* const* d_in, const int* in_sizes, int n_in,
                              void* d_out, int out_size, void* d_ws, size_t ws_size,
                              hipStream_t stream)
{
    const f4* data = (const f4*)d_in[0];
    const f4* seg  = (const f4*)d_in[1];
    f4* out = (f4*)d_out;

    constexpr unsigned block = 256;
    constexpr unsigned grid  = 2 * BPT;        // 12800 blocks, no tail
    crop_copy_kernel<<<grid, block, 0, stream>>>(data, seg, out);
}